// Round 3
// baseline (228.155 us; speedup 1.0000x reference)
//
#include <hip/hip_runtime.h>
#include <stdint.h>

#define B_  64
#define T_  256
#define C_  384
#define H_  6
#define D_  64
#define NTOK (B_*T_)   // 16384

typedef float f32x4  __attribute__((ext_vector_type(4)));
typedef short s16x8  __attribute__((ext_vector_type(8)));

__device__ __forceinline__ unsigned short f2bf(float f) {
    unsigned int u;
    __builtin_memcpy(&u, &f, 4);
    u = u + 0x7FFFu + ((u >> 16) & 1u);   // RNE
    return (unsigned short)(u >> 16);
}

// async 16B global -> LDS (lane i lands at ldsbase + i*16)
__device__ __forceinline__ void async_copy16(const unsigned short* g, unsigned short* l) {
    __builtin_amdgcn_global_load_lds(
        (const __attribute__((address_space(1))) unsigned int*)g,
        (__attribute__((address_space(3))) unsigned int*)l, 16, 0, 0);
}

// ---------------------------------------------------------------------------
// Kernel 0: convert + transpose weights f32 [R][Cc] -> bf16 [Cc][R].
// z<18: per-(proj,head) 384x64 -> W3 [h][proj*64+d][k] (per-HEAD contiguous
// [192][384] slab for the fused kernel); z==18: Wp -> WTp [384][384].
// ---------------------------------------------------------------------------
__global__ __launch_bounds__(256) void transpose_weights(
    const float* __restrict__ Wq, const float* __restrict__ Wk,
    const float* __restrict__ Wv, const float* __restrict__ Wp,
    unsigned short* __restrict__ W3, unsigned short* __restrict__ WTp) {
    __shared__ float tile[32][33];
    int z = blockIdx.y;
    const float* in;
    unsigned short* out;
    int R, Cc;
    if (z < 18) {
        int proj = z / 6, h = z % 6;
        const float* Wsrc = proj == 0 ? Wq : (proj == 1 ? Wk : Wv);
        in = Wsrc + h * C_ * D_;
        out = W3 + (size_t)(h * 192 + proj * 64) * C_;
        R = C_; Cc = D_;
    } else {
        in = Wp; out = WTp; R = C_; Cc = C_;
    }
    int tilesC = Cc / 32;
    int tilesR = R / 32;
    int bx = blockIdx.x;
    if (bx >= tilesC * tilesR) return;
    int tr = bx / tilesC, tc = bx % tilesC;
    int tx = threadIdx.x & 31;
    int ty8 = threadIdx.x >> 5;
    int gx = tc * 32 + tx;
#pragma unroll
    for (int i = 0; i < 4; i++) {
        int gy = tr * 32 + ty8 + i * 8;
        tile[ty8 + i * 8][tx] = in[gy * Cc + gx];
    }
    __syncthreads();
#pragma unroll
    for (int i = 0; i < 4; i++) {
        int oy = tc * 32 + ty8 + i * 8;
        int ox = tr * 32 + tx;
        out[oy * R + ox] = f2bf(tile[tx][ty8 + i * 8]);
    }
}

// ---------------------------------------------------------------------------
// Kernel 1: FUSED per-(b,h) QKV projection + causal attention.
// R2 post-mortem: the kernel is DS-pipe-bound; dur tracks LDS cycles.
// R3 structure: 16 waves.  Phase A: wave w = tile-pair p=w>>1 ({p,15-p},
// R0's proven dual-tile A-frag amortization: every B-frag feeds 2 MFMAs)
// x ni-half hh=w&1 (6 of 12 output n-tiles).  W fragments are read
// DIRECTLY FROM GLOBAL (147KB slab, L2-resident, shared by 64 blocks):
// this removes per block 2304 DMA->LDS writes + 1152 ds_read_b128 + all
// 8 Phase-A barriers (DS pipe now carries Phase B only).  Scatter formulas
// verbatim R0 (proven); Phase B verbatim R1 (one tile per wave).
// q/k/vT never touch global memory.
// ---------------------------------------------------------------------------
__global__ __launch_bounds__(1024, 4) void fused_attn(
    const float* __restrict__ X, const unsigned short* __restrict__ W3,
    unsigned short* __restrict__ Ows) {
    __shared__ alignas(16) unsigned short smem[67584];   // 132 KB
    // [0, 10240): per-wave Phase-B P scratch (16 x 640)
    unsigned short* q_lds  = smem + 18432;    // [256][64]
    unsigned short* k_lds  = q_lds + 16384;   // [256][64]
    unsigned short* vT_lds = k_lds + 16384;   // [64][256]

    int bh = blockIdx.x;
    int h = bh >> 6, b = bh & 63;
    int tid = threadIdx.x;
    int w = tid >> 6, lane = tid & 63;
    int n16 = lane & 15, q4 = lane >> 4;
    int p = w >> 1, hh = w & 1;               // Phase A: tile-pair / ni-half
    const int jt[2] = {p, 15 - p};
    const int ni0 = hh * 6;
    const int j = (w & 1) ? (15 - (w >> 1)) : (w >> 1);   // Phase B token-tile

    const unsigned short* W3h = W3 + (size_t)h * 192 * C_;
    const float* xb = X + (size_t)b * T_ * C_;

    f32x4 acc[2][6];
#pragma unroll
    for (int i = 0; i < 2; i++)
#pragma unroll
        for (int jj = 0; jj < 6; jj++) acc[i][jj] = (f32x4){0.f, 0.f, 0.f, 0.f};

    // ---------------- Phase A: q/k/v projection (no LDS, no barriers) -----
    for (int kc = 0; kc < 4; kc++) {
        int ko = kc * 96;
        // A-loads issued first (independent; hide under B-load latency)
        float4 a0[2][3], a1[2][3];
#pragma unroll
        for (int mi = 0; mi < 2; mi++)
#pragma unroll
            for (int ks = 0; ks < 3; ks++) {
                const float* ap = xb + (size_t)(jt[mi] * 16 + n16) * C_ + ko + ks * 32 + q4 * 8;
                a0[mi][ks] = *reinterpret_cast<const float4*>(ap);
                a1[mi][ks] = *reinterpret_cast<const float4*>(ap + 4);
            }
#pragma unroll
        for (int ks = 0; ks < 3; ks++) {
            s16x8 af[2];
#pragma unroll
            for (int mi = 0; mi < 2; mi++) {
                float4 lo = a0[mi][ks], hi = a1[mi][ks];
                s16x8 a;
                a[0] = (short)f2bf(lo.x); a[1] = (short)f2bf(lo.y);
                a[2] = (short)f2bf(lo.z); a[3] = (short)f2bf(lo.w);
                a[4] = (short)f2bf(hi.x); a[5] = (short)f2bf(hi.y);
                a[6] = (short)f2bf(hi.z); a[7] = (short)f2bf(hi.w);
                af[mi] = a;
            }
#pragma unroll
            for (int i = 0; i < 6; i++) {
                int ni = ni0 + i;
                int row = ni * 16 + n16;
                // B-frag straight from L2-resident W3h (row-major [192][384])
                s16x8 bf = *reinterpret_cast<const s16x8*>(
                    W3h + (size_t)row * C_ + ko + ks * 32 + q4 * 8);
                if (ni < 8) {   // q,k: swapped -> lane = token
                    acc[0][i] = __builtin_amdgcn_mfma_f32_16x16x32_bf16(bf, af[0], acc[0][i], 0, 0, 0);
                    acc[1][i] = __builtin_amdgcn_mfma_f32_16x16x32_bf16(bf, af[1], acc[1][i], 0, 0, 0);
                } else {        // v: normal -> lane = d-col
                    acc[0][i] = __builtin_amdgcn_mfma_f32_16x16x32_bf16(af[0], bf, acc[0][i], 0, 0, 0);
                    acc[1][i] = __builtin_amdgcn_mfma_f32_16x16x32_bf16(af[1], bf, acc[1][i], 0, 0, 0);
                }
            }
        }
    }
    // epilogue: scatter q/k/vT into XOR-chunked LDS (formulas verbatim R0)
#pragma unroll
    for (int mi = 0; mi < 2; mi++) {
        int tile = jt[mi];
#pragma unroll
        for (int i = 0; i < 6; i++) {
            int ni = ni0 + i;
            ushort4 pk;
            pk.x = f2bf(acc[mi][i][0]); pk.y = f2bf(acc[mi][i][1]);
            pk.z = f2bf(acc[mi][i][2]); pk.w = f2bf(acc[mi][i][3]);
            if (ni < 8) {
                int t = tile * 16 + n16;                       // lane = token
                int cp = (2 * (ni & 3) + (q4 >> 1)) ^ (n16 & 7);
                unsigned short* dst = (ni < 4) ? q_lds : k_lds;
                *reinterpret_cast<ushort4*>(&dst[t * 64 + cp * 8 + (q4 & 1) * 4]) = pk;
            } else {
                int d = (ni - 8) * 16 + n16;                   // lane = d
                int cp = (tile * 2 + (q4 >> 1)) ^ (d & 7);
                *reinterpret_cast<ushort4*>(&vT_lds[d * 256 + cp * 8 + (q4 & 1) * 4]) = pk;
            }
        }
    }
    __syncthreads();

    // ---------------- Phase B: causal attention from LDS (tile j) ---------
    unsigned short* pw = smem + w * 640;   // per-wave P scratch
    const f32x4 zero4 = (f32x4){0.f, 0.f, 0.f, 0.f};

    {
        int t0 = j * 16;
        int tq = t0 + n16;
        s16x8 qa0 = *reinterpret_cast<const s16x8*>(&q_lds[tq * 64 + ((q4 ^ (n16 & 7)) * 8)]);
        s16x8 qa1 = *reinterpret_cast<const s16x8*>(&q_lds[tq * 64 + (((q4 + 4) ^ (n16 & 7)) * 8)]);

        f32x4 o[4];
        float l_lane[4];
#pragma unroll
        for (int i = 0; i < 4; i++) o[i] = zero4;
#pragma unroll
        for (int r = 0; r < 4; r++) l_lane[r] = 0.f;

        int nch = j / 2 + 1;
        for (int c = 0; c < nch; c++) {
            int s0 = c * 32;
            bool bAct = (s0 + 16) < (t0 + 16);
            int r0 = s0 + n16, r1 = s0 + 16 + n16;
            s16x8 k00 = *reinterpret_cast<const s16x8*>(&k_lds[r0 * 64 + ((q4 ^ (r0 & 7)) * 8)]);
            s16x8 k01 = *reinterpret_cast<const s16x8*>(&k_lds[r0 * 64 + (((q4 + 4) ^ (r0 & 7)) * 8)]);
            f32x4 sv0 = __builtin_amdgcn_mfma_f32_16x16x32_bf16(qa0, k00, zero4, 0, 0, 0);
            sv0 = __builtin_amdgcn_mfma_f32_16x16x32_bf16(qa1, k01, sv0, 0, 0, 0);
            f32x4 sv1 = zero4;
            if (bAct) {
                s16x8 k10 = *reinterpret_cast<const s16x8*>(&k_lds[r1 * 64 + ((q4 ^ (r1 & 7)) * 8)]);
                s16x8 k11 = *reinterpret_cast<const s16x8*>(&k_lds[r1 * 64 + (((q4 + 4) ^ (r1 & 7)) * 8)]);
                sv1 = __builtin_amdgcn_mfma_f32_16x16x32_bf16(qa0, k10, zero4, 0, 0, 0);
                sv1 = __builtin_amdgcn_mfma_f32_16x16x32_bf16(qa1, k11, sv1, 0, 0, 0);
            }
#pragma unroll
            for (int r = 0; r < 4; r++) {
                int t = t0 + q4 * 4 + r;
                float pA = (s0 + n16 <= t) ? __expf(sv0[r] * 0.125f) : 0.f;
                float pB = (bAct && (s0 + 16 + n16 <= t)) ? __expf(sv1[r] * 0.125f) : 0.f;
                l_lane[r] += pA + pB;
                pw[(q4 * 4 + r) * 40 + n16] = f2bf(pA);
                pw[(q4 * 4 + r) * 40 + 16 + n16] = f2bf(pB);
            }
            s16x8 pa = *reinterpret_cast<const s16x8*>(&pw[n16 * 40 + q4 * 8]);
#pragma unroll
            for (int dt = 0; dt < 4; dt++) {
                int d = dt * 16 + n16;
                int jp = (c * 4 + q4) ^ (d & 7);
                s16x8 vf = *reinterpret_cast<const s16x8*>(&vT_lds[d * 256 + jp * 8]);
                o[dt] = __builtin_amdgcn_mfma_f32_16x16x32_bf16(pa, vf, o[dt], 0, 0, 0);
            }
        }

        float linv[4];
#pragma unroll
        for (int r = 0; r < 4; r++) {
            float l = l_lane[r];
            l += __shfl_xor(l, 1);
            l += __shfl_xor(l, 2);
            l += __shfl_xor(l, 4);
            l += __shfl_xor(l, 8);
            linv[r] = 1.0f / l;
        }
#pragma unroll
        for (int dt = 0; dt < 4; dt++) {
            int col = h * 64 + dt * 16 + n16;
#pragma unroll
            for (int r = 0; r < 4; r++)
                Ows[(size_t)(b * T_ + t0 + q4 * 4 + r) * C_ + col] = f2bf(o[dt][r] * linv[r]);
        }
    }
}

// ---------------------------------------------------------------------------
// Kernel 2: output projection + bias -> f32.  R6 structure (A-prefetch +
// DMA-staged B).  grid (128, 3), wave = 32 rows x 128 cols, swapped MFMA.
// ---------------------------------------------------------------------------
__global__ __launch_bounds__(256) void gemm_out(
    const unsigned short* __restrict__ A, const unsigned short* __restrict__ WTp,
    const float* __restrict__ bp, float* __restrict__ out) {
    __shared__ alignas(16) unsigned short Bt[6 * 128 * 32];   // 48 KB
    int m0 = blockIdx.x * 128;
    int n0 = blockIdx.y * 128;
    int tid = threadIdx.x;
    int w = tid >> 6, lane = tid & 63;
    int n16 = lane & 15, q4 = lane >> 4;

    f32x4 acc[2][8];
#pragma unroll
    for (int i = 0; i < 2; i++)
#pragma unroll
        for (int j = 0; j < 8; j++) acc[i][j] = (f32x4){0.f, 0.f, 0.f, 0.f};

    const unsigned short* a_base[2];
#pragma unroll
    for (int mi = 0; mi < 2; mi++)
        a_base[mi] = A + (size_t)(m0 + w * 32 + mi * 16 + n16) * C_ + q4 * 8;

    for (int half = 0; half < 2; half++) {
        int ko = half * 192;
        s16x8 af[2][6];
#pragma unroll
        for (int mi = 0; mi < 2; mi++)
#pragma unroll
            for (int ks = 0; ks < 6; ks++)
                af[mi][ks] = *reinterpret_cast<const s16x8*>(a_base[mi] + ko + ks * 32);
        if (half) __syncthreads();
#pragma unroll
        for (int i = 0; i < 12; i++) {
            int L = w * 768 + i * 64 + lane;
            int kstep = L >> 9;
            int rem = L & 511;
            int row = rem >> 2;
            int j = (rem & 3) ^ (row & 3);
            async_copy16(WTp + (size_t)(n0 + row) * C_ + ko + kstep * 32 + j * 8,
                         Bt + (size_t)(w * 768 + i * 64) * 8);
        }
        __syncthreads();
#pragma unroll
        for (int ks = 0; ks < 6; ks++) {
            s16x8 bf[8];
#pragma unroll
            for (int ni = 0; ni < 8; ni++) {
                int row = ni * 16 + n16;
                int jp = q4 ^ (row & 3);
                bf[ni] = *reinterpret_cast<const s16x8*>(&Bt[ks * 4096 + row * 32 + jp * 8]);
            }
#pragma unroll
            for (int mi = 0; mi < 2; mi++)
#pragma unroll
                for (int ni = 0; ni < 8; ni++)
                    acc[mi][ni] = __builtin_amdgcn_mfma_f32_16x16x32_bf16(
                        bf[ni], af[mi][ks], acc[mi][ni], 0, 0, 0);
        }
    }

#pragma unroll
    for (int mi = 0; mi < 2; mi++) {
        int tr = m0 + w * 32 + mi * 16 + n16;
#pragma unroll
        for (int ni = 0; ni < 8; ni++) {
            int c0 = n0 + ni * 16 + q4 * 4;
            float4 bias = *reinterpret_cast<const float4*>(&bp[c0]);
            float4 res;
            res.x = acc[mi][ni][0] + bias.x;
            res.y = acc[mi][ni][1] + bias.y;
            res.z = acc[mi][ni][2] + bias.z;
            res.w = acc[mi][ni][3] + bias.w;
            *reinterpret_cast<float4*>(&out[(size_t)tr * C_ + c0]) = res;
        }
    }
}

// ---------------------------------------------------------------------------
extern "C" void kernel_launch(void* const* d_in, const int* in_sizes, int n_in,
                              void* d_out, int out_size, void* d_ws, size_t ws_size,
                              hipStream_t stream) {
    const float* x  = (const float*)d_in[0];
    const float* Wq = (const float*)d_in[1];
    const float* Wk = (const float*)d_in[2];
    const float* Wv = (const float*)d_in[3];
    const float* Wp = (const float*)d_in[4];
    const float* bp = (const float*)d_in[5];
    float* out = (float*)d_out;

    char* ws = (char*)d_ws;
    size_t off = 0;
    auto alloc = [&](size_t bytes) -> unsigned short* {
        unsigned short* p = (unsigned short*)(ws + off);
        off += (bytes + 255) & ~(size_t)255;
        return p;
    };
    unsigned short* W3  = alloc((size_t)H_ * 192 * C_ * 2);  // 884 KB
    unsigned short* WTp = alloc((size_t)C_ * C_ * 2);        // 295 KB
    unsigned short* Ows = alloc((size_t)NTOK * C_ * 2);      // 12.6 MB

    transpose_weights<<<dim3(144, 19), dim3(256), 0, stream>>>(
        Wq, Wk, Wv, Wp, W3, WTp);
    fused_attn<<<dim3(B_ * H_), dim3(1024), 0, stream>>>(x, W3, Ows);
    gemm_out<<<dim3(128, 3), dim3(256), 0, stream>>>(Ows, WTp, bp, out);
}

// Round 4
// 170.883 us; speedup vs baseline: 1.3351x; 1.3351x over previous
//
#include <hip/hip_runtime.h>
#include <stdint.h>

#define B_  64
#define T_  256
#define C_  384
#define H_  6
#define D_  64
#define NTOK (B_*T_)   // 16384

typedef float f32x4  __attribute__((ext_vector_type(4)));
typedef short s16x8  __attribute__((ext_vector_type(8)));

__device__ __forceinline__ unsigned short f2bf(float f) {
    unsigned int u;
    __builtin_memcpy(&u, &f, 4);
    u = u + 0x7FFFu + ((u >> 16) & 1u);   // RNE
    return (unsigned short)(u >> 16);
}

// async 16B global -> LDS (lane i lands at ldsbase + i*16)
__device__ __forceinline__ void async_copy16(const unsigned short* g, unsigned short* l) {
    __builtin_amdgcn_global_load_lds(
        (const __attribute__((address_space(1))) unsigned int*)g,
        (__attribute__((address_space(3))) unsigned int*)l, 16, 0, 0);
}

// ---------------------------------------------------------------------------
// Kernel 0: convert + transpose weights f32 [R][Cc] -> bf16 [Cc][R].
// z<18: per-(proj,head) 384x64 -> W3 [h][proj*64+d][k] (per-HEAD contiguous
// [192][384] slab for the fused kernel); z==18: Wp -> WTp [384][384].
// ---------------------------------------------------------------------------
__global__ __launch_bounds__(256) void transpose_weights(
    const float* __restrict__ Wq, const float* __restrict__ Wk,
    const float* __restrict__ Wv, const float* __restrict__ Wp,
    unsigned short* __restrict__ W3, unsigned short* __restrict__ WTp) {
    __shared__ float tile[32][33];
    int z = blockIdx.y;
    const float* in;
    unsigned short* out;
    int R, Cc;
    if (z < 18) {
        int proj = z / 6, h = z % 6;
        const float* Wsrc = proj == 0 ? Wq : (proj == 1 ? Wk : Wv);
        in = Wsrc + h * C_ * D_;
        out = W3 + (size_t)(h * 192 + proj * 64) * C_;
        R = C_; Cc = D_;
    } else {
        in = Wp; out = WTp; R = C_; Cc = C_;
    }
    int tilesC = Cc / 32;
    int tilesR = R / 32;
    int bx = blockIdx.x;
    if (bx >= tilesC * tilesR) return;
    int tr = bx / tilesC, tc = bx % tilesC;
    int tx = threadIdx.x & 31;
    int ty8 = threadIdx.x >> 5;
    int gx = tc * 32 + tx;
#pragma unroll
    for (int i = 0; i < 4; i++) {
        int gy = tr * 32 + ty8 + i * 8;
        tile[ty8 + i * 8][tx] = in[gy * Cc + gx];
    }
    __syncthreads();
#pragma unroll
    for (int i = 0; i < 4; i++) {
        int oy = tc * 32 + ty8 + i * 8;
        int ox = tr * 32 + tx;
        out[oy * R + ox] = f2bf(tile[tx][ty8 + i * 8]);
    }
}

// ---------------------------------------------------------------------------
// Kernel 1: FUSED per-(b,h) QKV projection + causal attention.
// R3 post-mortem: global-direct B-reads thrashed L2 (FETCH+12MB, WRITE+23MB,
// 139us) -> staging through LDS is mandatory.  R4 completes the 2x2 matrix
// {waves/SIMD} x {DS load}: 16 waves (4/SIMD, R1's occupancy) AND dual-tile
// B-frag amortization (R0's DS efficiency: every staged B-frag feeds 2
// MFMAs).  Wave w = tile-pair p=w>>1 ({p,15-p}) x ni-half hh=w&1 (6 of 12
// n-tiles); B-frag ds_read_b128 per block = 16*4*3*6 = 1152 = R0's count at
// double R0's occupancy.  Staging/DMA/swizzle verbatim R1 (proven); Phase-A
// indexing + scatter verbatim R3 (proven); Phase B verbatim R1 (proven).
// If dur stays ~60-62us, the per-kc barrier-drain structure is the floor ->
// R5 attacks double-buffering.
// ---------------------------------------------------------------------------
__global__ __launch_bounds__(1024, 4) void fused_attn(
    const float* __restrict__ X, const unsigned short* __restrict__ W3,
    unsigned short* __restrict__ Ows) {
    __shared__ alignas(16) unsigned short smem[67584];   // 132 KB
    unsigned short* Wc     = smem;            // [192][96] chunk; phase-B pw aliases this
    unsigned short* q_lds  = smem + 18432;    // [256][64]
    unsigned short* k_lds  = q_lds + 16384;   // [256][64]
    unsigned short* vT_lds = k_lds + 16384;   // [64][256]

    int bh = blockIdx.x;
    int h = bh >> 6, b = bh & 63;
    int tid = threadIdx.x;
    int w = tid >> 6, lane = tid & 63;
    int n16 = lane & 15, q4 = lane >> 4;
    int p = w >> 1, hh = w & 1;               // Phase A: tile-pair / ni-half
    const int jt[2] = {p, 15 - p};
    const int ni0 = hh * 6;
    const int j = (w & 1) ? (15 - (w >> 1)) : (w >> 1);   // Phase B token-tile

    const unsigned short* W3h = W3 + (size_t)h * 192 * C_;
    const float* xb = X + (size_t)b * T_ * C_;

    f32x4 acc[2][6];
#pragma unroll
    for (int i = 0; i < 2; i++)
#pragma unroll
        for (int jj = 0; jj < 6; jj++) acc[i][jj] = (f32x4){0.f, 0.f, 0.f, 0.f};

    // ---------------- Phase A: q/k/v projection ----------------
    for (int kc = 0; kc < 4; kc++) {
        int ko = kc * 96;
        // A-loads issued first (overlap the staging + barrier)
        float4 a0[2][3], a1[2][3];
#pragma unroll
        for (int mi = 0; mi < 2; mi++)
#pragma unroll
            for (int ks = 0; ks < 3; ks++) {
                const float* ap = xb + (size_t)(jt[mi] * 16 + n16) * C_ + ko + ks * 32 + q4 * 8;
                a0[mi][ks] = *reinterpret_cast<const float4*>(ap);
                a1[mi][ks] = *reinterpret_cast<const float4*>(ap + 4);
            }
        if (kc) __syncthreads();   // prev chunk's readers done
        // stage W chunk [192 rows][12 chunks of 16B], slot L: row=L/12,
        // logical chunk c=L%12 holds global (ks=c>>2, q4g=(c&3)^(row&3))
#pragma unroll
        for (int i = 0; i < 3; i++) {
            int sb = i * 1024 + w * 64;       // wave-uniform
            if (sb < 2304) {
                int L = sb + lane;
                int row = L / 12;
                int c = L % 12;
                int ks = c >> 2;
                int q4g = (c & 3) ^ (row & 3);
                async_copy16(W3h + (size_t)row * C_ + ko + ks * 32 + q4g * 8,
                             Wc + (size_t)sb * 8);
            }
        }
        __syncthreads();   // drains DMA + A-loads
#pragma unroll
        for (int ks = 0; ks < 3; ks++) {
            s16x8 af[2];
#pragma unroll
            for (int mi = 0; mi < 2; mi++) {
                float4 lo = a0[mi][ks], hi = a1[mi][ks];
                s16x8 a;
                a[0] = (short)f2bf(lo.x); a[1] = (short)f2bf(lo.y);
                a[2] = (short)f2bf(lo.z); a[3] = (short)f2bf(lo.w);
                a[4] = (short)f2bf(hi.x); a[5] = (short)f2bf(hi.y);
                a[6] = (short)f2bf(hi.z); a[7] = (short)f2bf(hi.w);
                af[mi] = a;
            }
#pragma unroll
            for (int i = 0; i < 6; i++) {
                int ni = ni0 + i;
                int row = ni * 16 + n16;
                int cp = ks * 4 + (q4 ^ (row & 3));
                s16x8 bf = *reinterpret_cast<const s16x8*>(&Wc[row * 96 + cp * 8]);
                if (ni < 8) {   // q,k: swapped -> lane = token
                    acc[0][i] = __builtin_amdgcn_mfma_f32_16x16x32_bf16(bf, af[0], acc[0][i], 0, 0, 0);
                    acc[1][i] = __builtin_amdgcn_mfma_f32_16x16x32_bf16(bf, af[1], acc[1][i], 0, 0, 0);
                } else {        // v: normal -> lane = d-col
                    acc[0][i] = __builtin_amdgcn_mfma_f32_16x16x32_bf16(af[0], bf, acc[0][i], 0, 0, 0);
                    acc[1][i] = __builtin_amdgcn_mfma_f32_16x16x32_bf16(af[1], bf, acc[1][i], 0, 0, 0);
                }
            }
        }
    }
    // epilogue: scatter q/k/vT into XOR-chunked LDS (formulas verbatim R0/R3)
#pragma unroll
    for (int mi = 0; mi < 2; mi++) {
        int tile = jt[mi];
#pragma unroll
        for (int i = 0; i < 6; i++) {
            int ni = ni0 + i;
            ushort4 pk;
            pk.x = f2bf(acc[mi][i][0]); pk.y = f2bf(acc[mi][i][1]);
            pk.z = f2bf(acc[mi][i][2]); pk.w = f2bf(acc[mi][i][3]);
            if (ni < 8) {
                int t = tile * 16 + n16;                       // lane = token
                int cp = (2 * (ni & 3) + (q4 >> 1)) ^ (n16 & 7);
                unsigned short* dst = (ni < 4) ? q_lds : k_lds;
                *reinterpret_cast<ushort4*>(&dst[t * 64 + cp * 8 + (q4 & 1) * 4]) = pk;
            } else {
                int d = (ni - 8) * 16 + n16;                   // lane = d
                int cp = (tile * 2 + (q4 >> 1)) ^ (d & 7);
                *reinterpret_cast<ushort4*>(&vT_lds[d * 256 + cp * 8 + (q4 & 1) * 4]) = pk;
            }
        }
    }
    __syncthreads();

    // ---------------- Phase B: causal attention from LDS (tile j) ---------
    unsigned short* pw = smem + w * 640;   // per-wave P scratch (aliases Wc; safe post-barrier)
    const f32x4 zero4 = (f32x4){0.f, 0.f, 0.f, 0.f};

    {
        int t0 = j * 16;
        int tq = t0 + n16;
        s16x8 qa0 = *reinterpret_cast<const s16x8*>(&q_lds[tq * 64 + ((q4 ^ (n16 & 7)) * 8)]);
        s16x8 qa1 = *reinterpret_cast<const s16x8*>(&q_lds[tq * 64 + (((q4 + 4) ^ (n16 & 7)) * 8)]);

        f32x4 o[4];
        float l_lane[4];
#pragma unroll
        for (int i = 0; i < 4; i++) o[i] = zero4;
#pragma unroll
        for (int r = 0; r < 4; r++) l_lane[r] = 0.f;

        int nch = j / 2 + 1;
        for (int c = 0; c < nch; c++) {
            int s0 = c * 32;
            bool bAct = (s0 + 16) < (t0 + 16);
            int r0 = s0 + n16, r1 = s0 + 16 + n16;
            s16x8 k00 = *reinterpret_cast<const s16x8*>(&k_lds[r0 * 64 + ((q4 ^ (r0 & 7)) * 8)]);
            s16x8 k01 = *reinterpret_cast<const s16x8*>(&k_lds[r0 * 64 + (((q4 + 4) ^ (r0 & 7)) * 8)]);
            f32x4 sv0 = __builtin_amdgcn_mfma_f32_16x16x32_bf16(qa0, k00, zero4, 0, 0, 0);
            sv0 = __builtin_amdgcn_mfma_f32_16x16x32_bf16(qa1, k01, sv0, 0, 0, 0);
            f32x4 sv1 = zero4;
            if (bAct) {
                s16x8 k10 = *reinterpret_cast<const s16x8*>(&k_lds[r1 * 64 + ((q4 ^ (r1 & 7)) * 8)]);
                s16x8 k11 = *reinterpret_cast<const s16x8*>(&k_lds[r1 * 64 + (((q4 + 4) ^ (r1 & 7)) * 8)]);
                sv1 = __builtin_amdgcn_mfma_f32_16x16x32_bf16(qa0, k10, zero4, 0, 0, 0);
                sv1 = __builtin_amdgcn_mfma_f32_16x16x32_bf16(qa1, k11, sv1, 0, 0, 0);
            }
#pragma unroll
            for (int r = 0; r < 4; r++) {
                int t = t0 + q4 * 4 + r;
                float pA = (s0 + n16 <= t) ? __expf(sv0[r] * 0.125f) : 0.f;
                float pB = (bAct && (s0 + 16 + n16 <= t)) ? __expf(sv1[r] * 0.125f) : 0.f;
                l_lane[r] += pA + pB;
                pw[(q4 * 4 + r) * 40 + n16] = f2bf(pA);
                pw[(q4 * 4 + r) * 40 + 16 + n16] = f2bf(pB);
            }
            s16x8 pa = *reinterpret_cast<const s16x8*>(&pw[n16 * 40 + q4 * 8]);
#pragma unroll
            for (int dt = 0; dt < 4; dt++) {
                int d = dt * 16 + n16;
                int jp = (c * 4 + q4) ^ (d & 7);
                s16x8 vf = *reinterpret_cast<const s16x8*>(&vT_lds[d * 256 + jp * 8]);
                o[dt] = __builtin_amdgcn_mfma_f32_16x16x32_bf16(pa, vf, o[dt], 0, 0, 0);
            }
        }

        float linv[4];
#pragma unroll
        for (int r = 0; r < 4; r++) {
            float l = l_lane[r];
            l += __shfl_xor(l, 1);
            l += __shfl_xor(l, 2);
            l += __shfl_xor(l, 4);
            l += __shfl_xor(l, 8);
            linv[r] = 1.0f / l;
        }
#pragma unroll
        for (int dt = 0; dt < 4; dt++) {
            int col = h * 64 + dt * 16 + n16;
#pragma unroll
            for (int r = 0; r < 4; r++)
                Ows[(size_t)(b * T_ + t0 + q4 * 4 + r) * C_ + col] = f2bf(o[dt][r] * linv[r]);
        }
    }
}

// ---------------------------------------------------------------------------
// Kernel 2: output projection + bias -> f32.  R6 structure (A-prefetch +
// DMA-staged B).  grid (128, 3), wave = 32 rows x 128 cols, swapped MFMA.
// ---------------------------------------------------------------------------
__global__ __launch_bounds__(256) void gemm_out(
    const unsigned short* __restrict__ A, const unsigned short* __restrict__ WTp,
    const float* __restrict__ bp, float* __restrict__ out) {
    __shared__ alignas(16) unsigned short Bt[6 * 128 * 32];   // 48 KB
    int m0 = blockIdx.x * 128;
    int n0 = blockIdx.y * 128;
    int tid = threadIdx.x;
    int w = tid >> 6, lane = tid & 63;
    int n16 = lane & 15, q4 = lane >> 4;

    f32x4 acc[2][8];
#pragma unroll
    for (int i = 0; i < 2; i++)
#pragma unroll
        for (int j = 0; j < 8; j++) acc[i][j] = (f32x4){0.f, 0.f, 0.f, 0.f};

    const unsigned short* a_base[2];
#pragma unroll
    for (int mi = 0; mi < 2; mi++)
        a_base[mi] = A + (size_t)(m0 + w * 32 + mi * 16 + n16) * C_ + q4 * 8;

    for (int half = 0; half < 2; half++) {
        int ko = half * 192;
        s16x8 af[2][6];
#pragma unroll
        for (int mi = 0; mi < 2; mi++)
#pragma unroll
            for (int ks = 0; ks < 6; ks++)
                af[mi][ks] = *reinterpret_cast<const s16x8*>(a_base[mi] + ko + ks * 32);
        if (half) __syncthreads();
#pragma unroll
        for (int i = 0; i < 12; i++) {
            int L = w * 768 + i * 64 + lane;
            int kstep = L >> 9;
            int rem = L & 511;
            int row = rem >> 2;
            int j = (rem & 3) ^ (row & 3);
            async_copy16(WTp + (size_t)(n0 + row) * C_ + ko + kstep * 32 + j * 8,
                         Bt + (size_t)(w * 768 + i * 64) * 8);
        }
        __syncthreads();
#pragma unroll
        for (int ks = 0; ks < 6; ks++) {
            s16x8 bf[8];
#pragma unroll
            for (int ni = 0; ni < 8; ni++) {
                int row = ni * 16 + n16;
                int jp = q4 ^ (row & 3);
                bf[ni] = *reinterpret_cast<const s16x8*>(&Bt[ks * 4096 + row * 32 + jp * 8]);
            }
#pragma unroll
            for (int mi = 0; mi < 2; mi++)
#pragma unroll
                for (int ni = 0; ni < 8; ni++)
                    acc[mi][ni] = __builtin_amdgcn_mfma_f32_16x16x32_bf16(
                        bf[ni], af[mi][ks], acc[mi][ni], 0, 0, 0);
        }
    }

#pragma unroll
    for (int mi = 0; mi < 2; mi++) {
        int tr = m0 + w * 32 + mi * 16 + n16;
#pragma unroll
        for (int ni = 0; ni < 8; ni++) {
            int c0 = n0 + ni * 16 + q4 * 4;
            float4 bias = *reinterpret_cast<const float4*>(&bp[c0]);
            float4 res;
            res.x = acc[mi][ni][0] + bias.x;
            res.y = acc[mi][ni][1] + bias.y;
            res.z = acc[mi][ni][2] + bias.z;
            res.w = acc[mi][ni][3] + bias.w;
            *reinterpret_cast<float4*>(&out[(size_t)tr * C_ + c0]) = res;
        }
    }
}

// ---------------------------------------------------------------------------
extern "C" void kernel_launch(void* const* d_in, const int* in_sizes, int n_in,
                              void* d_out, int out_size, void* d_ws, size_t ws_size,
                              hipStream_t stream) {
    const float* x  = (const float*)d_in[0];
    const float* Wq = (const float*)d_in[1];
    const float* Wk = (const float*)d_in[2];
    const float* Wv = (const float*)d_in[3];
    const float* Wp = (const float*)d_in[4];
    const float* bp = (const float*)d_in[5];
    float* out = (float*)d_out;

    char* ws = (char*)d_ws;
    size_t off = 0;
    auto alloc = [&](size_t bytes) -> unsigned short* {
        unsigned short* p = (unsigned short*)(ws + off);
        off += (bytes + 255) & ~(size_t)255;
        return p;
    };
    unsigned short* W3  = alloc((size_t)H_ * 192 * C_ * 2);  // 884 KB
    unsigned short* WTp = alloc((size_t)C_ * C_ * 2);        // 295 KB
    unsigned short* Ows = alloc((size_t)NTOK * C_ * 2);      // 12.6 MB

    transpose_weights<<<dim3(144, 19), dim3(256), 0, stream>>>(
        Wq, Wk, Wv, Wp, W3, WTp);
    fused_attn<<<dim3(B_ * H_), dim3(1024), 0, stream>>>(x, W3, Ows);
    gemm_out<<<dim3(128, 3), dim3(256), 0, stream>>>(Ows, WTp, bp, out);
}

// Round 5
// 144.993 us; speedup vs baseline: 1.5736x; 1.1786x over previous
//
#include <hip/hip_runtime.h>
#include <stdint.h>

#define B_  64
#define T_  256
#define C_  384
#define H_  6
#define D_  64
#define NTOK (B_*T_)   // 16384

typedef float f32x4  __attribute__((ext_vector_type(4)));
typedef short s16x8  __attribute__((ext_vector_type(8)));

__device__ __forceinline__ unsigned short f2bf(float f) {
    unsigned int u;
    __builtin_memcpy(&u, &f, 4);
    u = u + 0x7FFFu + ((u >> 16) & 1u);   // RNE
    return (unsigned short)(u >> 16);
}

// async 16B global -> LDS (lane i lands at ldsbase + i*16)
__device__ __forceinline__ void async_copy16(const unsigned short* g, unsigned short* l) {
    __builtin_amdgcn_global_load_lds(
        (const __attribute__((address_space(1))) unsigned int*)g,
        (__attribute__((address_space(3))) unsigned int*)l, 16, 0, 0);
}

// ---------------------------------------------------------------------------
// Kernel 0: convert + transpose weights f32 [R][Cc] -> bf16 [Cc][R].
// z<18: per-(proj,head) 384x64 -> W3 [h][proj*64+d][k] (per-HEAD contiguous
// [192][384] slab for the fused kernel); z==18: Wp -> WTp [384][384].
// ---------------------------------------------------------------------------
__global__ __launch_bounds__(256) void transpose_weights(
    const float* __restrict__ Wq, const float* __restrict__ Wk,
    const float* __restrict__ Wv, const float* __restrict__ Wp,
    unsigned short* __restrict__ W3, unsigned short* __restrict__ WTp) {
    __shared__ float tile[32][33];
    int z = blockIdx.y;
    const float* in;
    unsigned short* out;
    int R, Cc;
    if (z < 18) {
        int proj = z / 6, h = z % 6;
        const float* Wsrc = proj == 0 ? Wq : (proj == 1 ? Wk : Wv);
        in = Wsrc + h * C_ * D_;
        out = W3 + (size_t)(h * 192 + proj * 64) * C_;
        R = C_; Cc = D_;
    } else {
        in = Wp; out = WTp; R = C_; Cc = C_;
    }
    int tilesC = Cc / 32;
    int tilesR = R / 32;
    int bx = blockIdx.x;
    if (bx >= tilesC * tilesR) return;
    int tr = bx / tilesC, tc = bx % tilesC;
    int tx = threadIdx.x & 31;
    int ty8 = threadIdx.x >> 5;
    int gx = tc * 32 + tx;
#pragma unroll
    for (int i = 0; i < 4; i++) {
        int gy = tr * 32 + ty8 + i * 8;
        tile[ty8 + i * 8][tx] = in[gy * Cc + gx];
    }
    __syncthreads();
#pragma unroll
    for (int i = 0; i < 4; i++) {
        int oy = tc * 32 + ty8 + i * 8;
        int ox = tr * 32 + tx;
        out[oy * R + ox] = f2bf(tile[tx][ty8 + i * 8]);
    }
}

// ---------------------------------------------------------------------------
// Kernel 1: FUSED per-(b,h) QKV projection + causal attention.
// R4 post-mortem: no pipe saturated (MFMA 10%, VALU 19%, HBM 8%, DS<50%);
// all configs floor at ~60us -> CU-level serialization: ONE 132KB block/CU =
// one barrier domain (all waves stall together at every vmcnt-drain) + 384
// blocks at 1/CU = 2 dispatch rounds (round 2 half-empty).
// R5: LDS 132KB -> 76KB => TWO independent blocks/CU (separate barrier
// domains overlap each other's stalls; single dispatch round).
//  - R0's proven 8-wave dual-tile structure (wave w owns tiles {w,15-w} in
//    both phases), acc[2][12].
//  - Wc chunk 96->32 K-cols ([192][32]=12KB, 12 kc), same DMA/XOR algebra;
//    A-loads pipelined one chunk ahead so barrier drains don't expose them.
//  - q eliminated from LDS (-32KB): same wave computes and consumes q-tile,
//    so C/D->A-frag relayout is in-register: 16 ds_bpermute + 8 cndmask per
//    tile (lane(n16,q4) pulls pk[q4>>1] / pk[2+(q4>>1)] dwords from lanes
//    n16+16*{2(q4&1), 2(q4&1)+1}).
//  - pw (single-buffer, 8x1280B) aliases the Wc region post-barrier.
// k/vT scatter + Phase B verbatim proven code.
// ---------------------------------------------------------------------------
__global__ __launch_bounds__(512, 4) void fused_attn(
    const float* __restrict__ X, const unsigned short* __restrict__ W3,
    unsigned short* __restrict__ Ows) {
    __shared__ alignas(16) unsigned short smem[38912];   // 76 KB -> 2 blocks/CU
    unsigned short* Wc     = smem;            // [192][32] staging; pw aliases post-barrier
    unsigned short* k_lds  = smem + 6144;     // [256][64]
    unsigned short* vT_lds = k_lds + 16384;   // [64][256]

    int bh = blockIdx.x;
    int h = bh >> 6, b = bh & 63;
    int tid = threadIdx.x;
    int w = tid >> 6, lane = tid & 63;
    int n16 = lane & 15, q4 = lane >> 4;
    const int jt[2] = {w, 15 - w};            // this wave's token-tiles (both phases)

    const unsigned short* W3h = W3 + (size_t)h * 192 * C_;
    const float* xb = X + (size_t)b * T_ * C_;

    f32x4 acc[2][12];
#pragma unroll
    for (int i = 0; i < 2; i++)
#pragma unroll
        for (int jj = 0; jj < 12; jj++) acc[i][jj] = (f32x4){0.f, 0.f, 0.f, 0.f};

    // ---------------- Phase A: q/k/v projection, 12 chunks of K=32 --------
    float4 a0[2], a1[2];
#pragma unroll
    for (int mi = 0; mi < 2; mi++) {          // preload chunk 0 A-frags
        const float* ap = xb + (size_t)(jt[mi] * 16 + n16) * C_ + q4 * 8;
        a0[mi] = *reinterpret_cast<const float4*>(ap);
        a1[mi] = *reinterpret_cast<const float4*>(ap + 4);
    }

    for (int kc = 0; kc < 12; kc++) {
        int ko = kc * 32;
        if (kc) __syncthreads();   // prev chunk's readers done
        // stage W chunk [192 rows][4 units of 16B]; slot L: row=L>>2, phys
        // unit c=L&3 holds logical unit c^(row&3) (same XOR algebra as R1)
        {
            int L = w * 64 + lane;
            int row = L >> 2, c = L & 3;
            async_copy16(W3h + (size_t)row * C_ + ko + ((c ^ (row & 3)) * 8),
                         Wc + (size_t)L * 8);
            if (w < 4) {
                int L2 = 512 + w * 64 + lane;
                int row2 = L2 >> 2, c2 = L2 & 3;
                async_copy16(W3h + (size_t)row2 * C_ + ko + ((c2 ^ (row2 & 3)) * 8),
                             Wc + (size_t)L2 * 8);
            }
        }
        __syncthreads();   // drains DMA (+ A-loads issued one chunk ago)
        s16x8 af[2];
#pragma unroll
        for (int mi = 0; mi < 2; mi++) {
            float4 lo = a0[mi], hi = a1[mi];
            s16x8 a;
            a[0] = (short)f2bf(lo.x); a[1] = (short)f2bf(lo.y);
            a[2] = (short)f2bf(lo.z); a[3] = (short)f2bf(lo.w);
            a[4] = (short)f2bf(hi.x); a[5] = (short)f2bf(hi.y);
            a[6] = (short)f2bf(hi.z); a[7] = (short)f2bf(hi.w);
            af[mi] = a;
        }
        if (kc < 11) {   // issue next chunk's A-loads; hidden under the MFMAs
#pragma unroll
            for (int mi = 0; mi < 2; mi++) {
                const float* ap = xb + (size_t)(jt[mi] * 16 + n16) * C_ + (ko + 32) + q4 * 8;
                a0[mi] = *reinterpret_cast<const float4*>(ap);
                a1[mi] = *reinterpret_cast<const float4*>(ap + 4);
            }
        }
#pragma unroll
        for (int ni = 0; ni < 12; ni++) {
            int row = ni * 16 + n16;
            s16x8 bf = *reinterpret_cast<const s16x8*>(&Wc[row * 32 + ((q4 ^ (row & 3)) * 8)]);
            if (ni < 8) {   // q,k: swapped -> lane = token
                acc[0][ni] = __builtin_amdgcn_mfma_f32_16x16x32_bf16(bf, af[0], acc[0][ni], 0, 0, 0);
                acc[1][ni] = __builtin_amdgcn_mfma_f32_16x16x32_bf16(bf, af[1], acc[1][ni], 0, 0, 0);
            } else {        // v: normal -> lane = d-col
                acc[0][ni] = __builtin_amdgcn_mfma_f32_16x16x32_bf16(af[0], bf, acc[0][ni], 0, 0, 0);
                acc[1][ni] = __builtin_amdgcn_mfma_f32_16x16x32_bf16(af[1], bf, acc[1][ni], 0, 0, 0);
            }
        }
    }

    // epilogue: k/vT scatter (verbatim proven), q kept in registers
    unsigned int qd[2][4][2];   // [tile][ni][dword]; all indices unroll-const
#pragma unroll
    for (int mi = 0; mi < 2; mi++) {
        int tile = jt[mi];
#pragma unroll
        for (int ni = 0; ni < 12; ni++) {
            ushort4 pk;
            pk.x = f2bf(acc[mi][ni][0]); pk.y = f2bf(acc[mi][ni][1]);
            pk.z = f2bf(acc[mi][ni][2]); pk.w = f2bf(acc[mi][ni][3]);
            if (ni < 4) {
                qd[mi][ni][0] = (unsigned int)pk.x | ((unsigned int)pk.y << 16);
                qd[mi][ni][1] = (unsigned int)pk.z | ((unsigned int)pk.w << 16);
            } else if (ni < 8) {
                int t = tile * 16 + n16;                       // lane = token
                int cp = (2 * (ni & 3) + (q4 >> 1)) ^ (n16 & 7);
                *reinterpret_cast<ushort4*>(&k_lds[t * 64 + cp * 8 + (q4 & 1) * 4]) = pk;
            } else {
                int d = (ni - 8) * 16 + n16;                   // lane = d
                int cp = (tile * 2 + (q4 >> 1)) ^ (d & 7);
                *reinterpret_cast<ushort4*>(&vT_lds[d * 256 + cp * 8 + (q4 & 1) * 4]) = pk;
            }
        }
    }

    // in-register q relayout: C/D frag (d = ni*16+q4*4+r) -> A-frag
    // (qa0: d = q4*8..+7, qa1: d = 32+q4*8..+7), same token row n16.
    s16x8 qa[2][2];
    {
        int addrA = (n16 + 32 * (q4 & 1)) * 4;
        int addrB = addrA + 64;
        bool hi = (q4 & 2) != 0;
#pragma unroll
        for (int mi = 0; mi < 2; mi++) {
#pragma unroll
            for (int half = 0; half < 2; half++) {
                unsigned int s0x = qd[mi][half * 2][0],     s0y = qd[mi][half * 2][1];
                unsigned int s1x = qd[mi][half * 2 + 1][0], s1y = qd[mi][half * 2 + 1][1];
                unsigned int A0x = (unsigned int)__builtin_amdgcn_ds_bpermute(addrA, (int)s0x);
                unsigned int A1x = (unsigned int)__builtin_amdgcn_ds_bpermute(addrA, (int)s1x);
                unsigned int A0y = (unsigned int)__builtin_amdgcn_ds_bpermute(addrA, (int)s0y);
                unsigned int A1y = (unsigned int)__builtin_amdgcn_ds_bpermute(addrA, (int)s1y);
                unsigned int B0x = (unsigned int)__builtin_amdgcn_ds_bpermute(addrB, (int)s0x);
                unsigned int B1x = (unsigned int)__builtin_amdgcn_ds_bpermute(addrB, (int)s1x);
                unsigned int B0y = (unsigned int)__builtin_amdgcn_ds_bpermute(addrB, (int)s0y);
                unsigned int B1y = (unsigned int)__builtin_amdgcn_ds_bpermute(addrB, (int)s1y);
                unsigned int t[4];
                t[0] = hi ? A1x : A0x;
                t[1] = hi ? A1y : A0y;
                t[2] = hi ? B1x : B0x;
                t[3] = hi ? B1y : B0y;
                s16x8 q;
                __builtin_memcpy(&q, t, 16);
                qa[mi][half] = q;
            }
        }
    }
    __syncthreads();

    // ---------------- Phase B: causal attention from LDS ----------------
    unsigned short* pw = smem + w * 640;   // aliases Wc region; safe post-barrier
    const f32x4 zero4 = (f32x4){0.f, 0.f, 0.f, 0.f};

#pragma unroll
    for (int tt = 0; tt < 2; tt++) {
        int j = jt[tt];
        int t0 = j * 16;
        s16x8 qa0 = qa[tt][0];
        s16x8 qa1 = qa[tt][1];

        f32x4 o[4];
        float l_lane[4];
#pragma unroll
        for (int i = 0; i < 4; i++) o[i] = zero4;
#pragma unroll
        for (int r = 0; r < 4; r++) l_lane[r] = 0.f;

        int nch = j / 2 + 1;
        for (int c = 0; c < nch; c++) {
            int s0 = c * 32;
            bool bAct = (s0 + 16) < (t0 + 16);
            int r0 = s0 + n16, r1 = s0 + 16 + n16;
            s16x8 k00 = *reinterpret_cast<const s16x8*>(&k_lds[r0 * 64 + ((q4 ^ (r0 & 7)) * 8)]);
            s16x8 k01 = *reinterpret_cast<const s16x8*>(&k_lds[r0 * 64 + (((q4 + 4) ^ (r0 & 7)) * 8)]);
            f32x4 sv0 = __builtin_amdgcn_mfma_f32_16x16x32_bf16(qa0, k00, zero4, 0, 0, 0);
            sv0 = __builtin_amdgcn_mfma_f32_16x16x32_bf16(qa1, k01, sv0, 0, 0, 0);
            f32x4 sv1 = zero4;
            if (bAct) {
                s16x8 k10 = *reinterpret_cast<const s16x8*>(&k_lds[r1 * 64 + ((q4 ^ (r1 & 7)) * 8)]);
                s16x8 k11 = *reinterpret_cast<const s16x8*>(&k_lds[r1 * 64 + (((q4 + 4) ^ (r1 & 7)) * 8)]);
                sv1 = __builtin_amdgcn_mfma_f32_16x16x32_bf16(qa0, k10, zero4, 0, 0, 0);
                sv1 = __builtin_amdgcn_mfma_f32_16x16x32_bf16(qa1, k11, sv1, 0, 0, 0);
            }
#pragma unroll
            for (int r = 0; r < 4; r++) {
                int t = t0 + q4 * 4 + r;
                float pA = (s0 + n16 <= t) ? __expf(sv0[r] * 0.125f) : 0.f;
                float pB = (bAct && (s0 + 16 + n16 <= t)) ? __expf(sv1[r] * 0.125f) : 0.f;
                l_lane[r] += pA + pB;
                pw[(q4 * 4 + r) * 40 + n16] = f2bf(pA);
                pw[(q4 * 4 + r) * 40 + 16 + n16] = f2bf(pB);
            }
            s16x8 pa = *reinterpret_cast<const s16x8*>(&pw[n16 * 40 + q4 * 8]);
#pragma unroll
            for (int dt = 0; dt < 4; dt++) {
                int d = dt * 16 + n16;
                int jp = (c * 4 + q4) ^ (d & 7);
                s16x8 vf = *reinterpret_cast<const s16x8*>(&vT_lds[d * 256 + jp * 8]);
                o[dt] = __builtin_amdgcn_mfma_f32_16x16x32_bf16(pa, vf, o[dt], 0, 0, 0);
            }
        }

        float linv[4];
#pragma unroll
        for (int r = 0; r < 4; r++) {
            float l = l_lane[r];
            l += __shfl_xor(l, 1);
            l += __shfl_xor(l, 2);
            l += __shfl_xor(l, 4);
            l += __shfl_xor(l, 8);
            linv[r] = 1.0f / l;
        }
#pragma unroll
        for (int dt = 0; dt < 4; dt++) {
            int col = h * 64 + dt * 16 + n16;
#pragma unroll
            for (int r = 0; r < 4; r++)
                Ows[(size_t)(b * T_ + t0 + q4 * 4 + r) * C_ + col] = f2bf(o[dt][r] * linv[r]);
        }
    }
}

// ---------------------------------------------------------------------------
// Kernel 2: output projection + bias -> f32.  R6 structure (A-prefetch +
// DMA-staged B).  grid (128, 3), wave = 32 rows x 128 cols, swapped MFMA.
// ---------------------------------------------------------------------------
__global__ __launch_bounds__(256) void gemm_out(
    const unsigned short* __restrict__ A, const unsigned short* __restrict__ WTp,
    const float* __restrict__ bp, float* __restrict__ out) {
    __shared__ alignas(16) unsigned short Bt[6 * 128 * 32];   // 48 KB
    int m0 = blockIdx.x * 128;
    int n0 = blockIdx.y * 128;
    int tid = threadIdx.x;
    int w = tid >> 6, lane = tid & 63;
    int n16 = lane & 15, q4 = lane >> 4;

    f32x4 acc[2][8];
#pragma unroll
    for (int i = 0; i < 2; i++)
#pragma unroll
        for (int j = 0; j < 8; j++) acc[i][j] = (f32x4){0.f, 0.f, 0.f, 0.f};

    const unsigned short* a_base[2];
#pragma unroll
    for (int mi = 0; mi < 2; mi++)
        a_base[mi] = A + (size_t)(m0 + w * 32 + mi * 16 + n16) * C_ + q4 * 8;

    for (int half = 0; half < 2; half++) {
        int ko = half * 192;
        s16x8 af[2][6];
#pragma unroll
        for (int mi = 0; mi < 2; mi++)
#pragma unroll
            for (int ks = 0; ks < 6; ks++)
                af[mi][ks] = *reinterpret_cast<const s16x8*>(a_base[mi] + ko + ks * 32);
        if (half) __syncthreads();
#pragma unroll
        for (int i = 0; i < 12; i++) {
            int L = w * 768 + i * 64 + lane;
            int kstep = L >> 9;
            int rem = L & 511;
            int row = rem >> 2;
            int j = (rem & 3) ^ (row & 3);
            async_copy16(WTp + (size_t)(n0 + row) * C_ + ko + kstep * 32 + j * 8,
                         Bt + (size_t)(w * 768 + i * 64) * 8);
        }
        __syncthreads();
#pragma unroll
        for (int ks = 0; ks < 6; ks++) {
            s16x8 bf[8];
#pragma unroll
            for (int ni = 0; ni < 8; ni++) {
                int row = ni * 16 + n16;
                int jp = q4 ^ (row & 3);
                bf[ni] = *reinterpret_cast<const s16x8*>(&Bt[ks * 4096 + row * 32 + jp * 8]);
            }
#pragma unroll
            for (int mi = 0; mi < 2; mi++)
#pragma unroll
                for (int ni = 0; ni < 8; ni++)
                    acc[mi][ni] = __builtin_amdgcn_mfma_f32_16x16x32_bf16(
                        bf[ni], af[mi][ks], acc[mi][ni], 0, 0, 0);
        }
    }

#pragma unroll
    for (int mi = 0; mi < 2; mi++) {
        int tr = m0 + w * 32 + mi * 16 + n16;
#pragma unroll
        for (int ni = 0; ni < 8; ni++) {
            int c0 = n0 + ni * 16 + q4 * 4;
            float4 bias = *reinterpret_cast<const float4*>(&bp[c0]);
            float4 res;
            res.x = acc[mi][ni][0] + bias.x;
            res.y = acc[mi][ni][1] + bias.y;
            res.z = acc[mi][ni][2] + bias.z;
            res.w = acc[mi][ni][3] + bias.w;
            *reinterpret_cast<float4*>(&out[(size_t)tr * C_ + c0]) = res;
        }
    }
}

// ---------------------------------------------------------------------------
extern "C" void kernel_launch(void* const* d_in, const int* in_sizes, int n_in,
                              void* d_out, int out_size, void* d_ws, size_t ws_size,
                              hipStream_t stream) {
    const float* x  = (const float*)d_in[0];
    const float* Wq = (const float*)d_in[1];
    const float* Wk = (const float*)d_in[2];
    const float* Wv = (const float*)d_in[3];
    const float* Wp = (const float*)d_in[4];
    const float* bp = (const float*)d_in[5];
    float* out = (float*)d_out;

    char* ws = (char*)d_ws;
    size_t off = 0;
    auto alloc = [&](size_t bytes) -> unsigned short* {
        unsigned short* p = (unsigned short*)(ws + off);
        off += (bytes + 255) & ~(size_t)255;
        return p;
    };
    unsigned short* W3  = alloc((size_t)H_ * 192 * C_ * 2);  // 884 KB
    unsigned short* WTp = alloc((size_t)C_ * C_ * 2);        // 295 KB
    unsigned short* Ows = alloc((size_t)NTOK * C_ * 2);      // 12.6 MB

    transpose_weights<<<dim3(144, 19), dim3(256), 0, stream>>>(
        Wq, Wk, Wv, Wp, W3, WTp);
    fused_attn<<<dim3(B_ * H_), dim3(512), 0, stream>>>(x, W3, Ows);
    gemm_out<<<dim3(128, 3), dim3(256), 0, stream>>>(Ows, WTp, bp, out);
}